// Round 1
// baseline (72.837 us; speedup 1.0000x reference)
//
#include <hip/hip_runtime.h>

// RandomFlipLR: (B=64, C=3, H=512, W=512) fp32, flip W per batch where mask[b]>0.
// Pure memory-bound: 192 MiB in + 192 MiB out. float4-vectorized, coalesced on
// the output; flipped loads read descending-but-contiguous addresses (coalesced).

#define B_ 64
#define C_ 3
#define H_ 512
#define W_ 512
#define WV (W_ / 4)              // 128 float4 per row
#define PER_B (C_ * H_ * WV)     // 196608 float4 per batch image

__global__ __launch_bounds__(256) void RandomFlipLR_71734543777923_kernel(
    const float4* __restrict__ in, const int* __restrict__ mask,
    float4* __restrict__ out) {
    const int b   = blockIdx.y;
    const int idx = blockIdx.x * blockDim.x + threadIdx.x;   // [0, PER_B)
    const long long base = (long long)b * PER_B;

    if (mask[b] > 0) {                       // wave-uniform branch
        const int wv  = idx & (WV - 1);
        const int row = idx >> 7;            // idx / WV
        float4 v = in[base + (long long)row * WV + (WV - 1 - wv)];
        out[base + idx] = make_float4(v.w, v.z, v.y, v.x);
    } else {
        out[base + idx] = in[base + idx];
    }
}

extern "C" void kernel_launch(void* const* d_in, const int* in_sizes, int n_in,
                              void* d_out, int out_size, void* d_ws, size_t ws_size,
                              hipStream_t stream) {
    const float4* in  = (const float4*)d_in[0];
    const int* mask   = (const int*)d_in[1];
    float4* out       = (float4*)d_out;

    dim3 block(256);
    dim3 grid(PER_B / 256, B_);              // 768 x 64 blocks
    RandomFlipLR_71734543777923_kernel<<<grid, block, 0, stream>>>(in, mask, out);
}

// Round 2
// 70.260 us; speedup vs baseline: 1.0367x; 1.0367x over previous
//
#include <hip/hip_runtime.h>

// RandomFlipLR: (B=64, C=3, H=512, W=512) fp32, flip W per batch where mask[b]>0.
// Pure memory-bound streaming: 192 MiB in + 192 MiB out, zero reuse.
// - float4 (16B/lane) loads/stores, coalesced on output
// - flipped source index = idx ^ 127 (128 float4/row, subtract-from-ones == XOR)
// - 8 float4 per thread in contiguous 32KiB/block chunks for ILP
// - nontemporal hints: streaming data, don't thrash L2/L3

typedef float f4 __attribute__((ext_vector_type(4)));

#define B_ 64
#define C_ 3
#define H_ 512
#define W_ 512
#define WV (W_ / 4)              // 128 float4 per row
#define PER_B (C_ * H_ * WV)     // 196608 float4 per batch image
#define ITERS 8
#define CHUNK (256 * ITERS)      // float4 per block

__global__ __launch_bounds__(256) void RandomFlipLR_71734543777923_kernel(
    const f4* __restrict__ in, const int* __restrict__ mask,
    f4* __restrict__ out) {
    const int b = blockIdx.y;
    const long long base = (long long)b * PER_B;
    const int tid   = threadIdx.x;
    const int chunk = blockIdx.x * CHUNK;

    f4 v[ITERS];
    if (mask[b] > 0) {                        // wave-uniform branch
        #pragma unroll
        for (int i = 0; i < ITERS; ++i) {
            const int idx = chunk + i * 256 + tid;
            f4 t = __builtin_nontemporal_load(&in[base + (idx ^ (WV - 1))]);
            v[i] = t.wzyx;
        }
    } else {
        #pragma unroll
        for (int i = 0; i < ITERS; ++i) {
            const int idx = chunk + i * 256 + tid;
            v[i] = __builtin_nontemporal_load(&in[base + idx]);
        }
    }
    #pragma unroll
    for (int i = 0; i < ITERS; ++i) {
        const int idx = chunk + i * 256 + tid;
        __builtin_nontemporal_store(v[i], &out[base + idx]);
    }
}

extern "C" void kernel_launch(void* const* d_in, const int* in_sizes, int n_in,
                              void* d_out, int out_size, void* d_ws, size_t ws_size,
                              hipStream_t stream) {
    const f4* in    = (const f4*)d_in[0];
    const int* mask = (const int*)d_in[1];
    f4* out         = (f4*)d_out;

    dim3 block(256);
    dim3 grid(PER_B / CHUNK, B_);            // 96 x 64 = 6144 blocks
    RandomFlipLR_71734543777923_kernel<<<grid, block, 0, stream>>>(in, mask, out);
}